// Round 2
// baseline (5838.869 us; speedup 1.0000x reference)
//
#include <hip/hip_runtime.h>
#include <hip/hip_bf16.h>
#include <stdint.h>

typedef __bf16 bf16_t;
typedef __attribute__((ext_vector_type(8))) __bf16 bf16x8;
typedef __attribute__((ext_vector_type(4))) __bf16 bf16x4;
typedef __attribute__((ext_vector_type(4))) float f32x4;
typedef __attribute__((ext_vector_type(16))) float f32x16;
#define LL long long

// ---- async global->LDS, 16B per lane. ldsptr must be wave-uniform. ----
__device__ __forceinline__ void gl_lds16(const bf16_t* g, bf16_t* s) {
  __builtin_amdgcn_global_load_lds(
      (const __attribute__((address_space(1))) void*)g,
      (__attribute__((address_space(3))) void*)s, 16, 0, 0);
}

__device__ __forceinline__ float sigm(float x) {
  return 1.0f / (1.0f + __expf(-x));
}
__device__ __forceinline__ float tanh_s(float x) {
  float e = __expf(-2.0f * fabsf(x));
  float t = (1.0f - e) / (1.0f + e);
  return copysignf(t, x);
}

// ======================= generic C = A @ B^T GEMM ========================
// A [M,K] bf16, B [N,K] bf16, bias fp32 [N]; tile BM x 128, BK=32.
// OUTBF=1: write bf16 to Cb + (fw[0] ? off1 : off0); else fp32 to Cf.
template<int BM, int OUTBF>
__global__ __launch_bounds__(256, 2)
void gemm_bt(const bf16_t* __restrict__ A, const bf16_t* __restrict__ B,
             const float* __restrict__ bias,
             bf16_t* __restrict__ Cb, float* __restrict__ Cf,
             int N, int K, const int* __restrict__ fw, LL off0, LL off1) {
  __shared__ bf16_t lds_a[BM * 32];
  __shared__ bf16_t lds_b[128 * 32];
  const int tid = threadIdx.x;
  const int w = tid >> 6, l = tid & 63;
  const LL m0 = (LL)blockIdx.x * BM;
  const LL n0 = (LL)blockIdx.y * 128;
  constexpr int MI = BM / 32;
  const int wm = w & 1, wn = w >> 1;
  f32x4 acc[MI][4] = {};

  const int srow = l >> 2;
  const int scol = (l & 3) * 8;

  for (int kt = 0; kt < K; kt += 32) {
    for (int c = w; c < BM / 16; c += 4)
      gl_lds16(A + (m0 + c * 16 + srow) * K + kt + scol, &lds_a[c * 512]);
#pragma unroll
    for (int j = 0; j < 2; ++j) {
      int c = w * 2 + j;
      gl_lds16(B + (n0 + c * 16 + srow) * K + kt + scol, &lds_b[c * 512]);
    }
    __syncthreads();
    const int fr = l & 15, fk = (l >> 4) * 8;
    bf16x8 af[MI], bfr[4];
#pragma unroll
    for (int i = 0; i < MI; ++i)
      af[i] = *(const bf16x8*)&lds_a[(wm * (BM / 2) + i * 16 + fr) * 32 + fk];
#pragma unroll
    for (int j = 0; j < 4; ++j)
      bfr[j] = *(const bf16x8*)&lds_b[(wn * 64 + j * 16 + fr) * 32 + fk];
#pragma unroll
    for (int i = 0; i < MI; ++i)
#pragma unroll
      for (int j = 0; j < 4; ++j)
        acc[i][j] = __builtin_amdgcn_mfma_f32_16x16x32_bf16(af[i], bfr[j],
                                                            acc[i][j], 0, 0, 0);
    __syncthreads();
  }

  const LL coff = (fw[0] ? off1 : off0);
  const int er = (l >> 4) * 4, ec = l & 15;
#pragma unroll
  for (int i = 0; i < MI; ++i) {
#pragma unroll
    for (int j = 0; j < 4; ++j) {
      LL mrow = m0 + wm * (BM / 2) + i * 16 + er;
      LL ncol = n0 + wn * 64 + j * 16 + ec;
      float bs = bias[ncol];
#pragma unroll
      for (int r = 0; r < 4; ++r) {
        float v = acc[i][j][r] + bs;
        if (OUTBF) Cb[coff + (mrow + r) * N + ncol] = (bf16_t)v;
        else       Cf[(mrow + r) * N + ncol] = v;
      }
    }
  }
}

// ==================== persistent recurrent kernel ====================
// Grid (64, 4): blockIdx.x = unit group j0=16*x, blockIdx.y = m-tile (128 rows).
// W_hh slice (4 gates x 16 units x 1024 K = 128 KB bf16) resident in LDS.
// A (h) loaded global->VGPR directly: NO barriers inside K-loop.
// c kept in registers for all 49 steps. Per-step sync: device-scope atomic
// counter among the 64 blocks sharing an m-tile; h ping-pongs hb0/hb1.
__global__ __launch_bounds__(256, 1)
void lstm_persist(const bf16_t* __restrict__ Whhb, const bf16_t* __restrict__ G,
                  bf16_t* hb0, bf16_t* hb1,
                  float* __restrict__ hid, int* cnt) {
  __shared__ bf16_t lds_b[64 * 1024];   // 128 KB, XOR-swizzled 16B blocks
  const int tid = threadIdx.x, w = tid >> 6, l = tid & 63;
  const int j0 = blockIdx.x * 16;
  const int mt = blockIdx.y;
  const int m0 = mt * 128;

  // one-time LDS fill: row ct (gate ct>>4, unit j0+(ct&15)), 16B block kb
  for (int i = tid; i < 8192; i += 256) {
    int ct = i >> 7, kb = i & 127;
    int srow = (ct >> 4) * 1024 + j0 + (ct & 15);
    bf16x8 v = *(const bf16x8*)(Whhb + (LL)srow * 1024 + kb * 8);
    *(bf16x8*)&lds_b[ct * 1024 + ((kb ^ (ct & 7)) << 3)] = v;
  }
  __syncthreads();

  const int cc = l & 31, kh = l >> 5;
  const int ga = cc >> 4;             // 0: lane acc holds gates (i,g); 1: (f,o)
  const int unit = j0 + (cc & 15);
  const int sw = cc & 7;
  float creg[8];
#pragma unroll
  for (int r = 0; r < 8; ++r) creg[r] = 0.f;

  bf16_t* hbuf[2] = {hb0, hb1};

  for (int t = 0; t < 49; ++t) {
    f32x16 acA = {}, acB = {}, acC = {}, acD = {};
    if (t > 0) {
      const bf16_t* hin = hbuf[(t - 1) & 1];
      const bf16_t* ap = hin + (LL)(m0 + w * 32 + cc) * 1024 + kh * 8;
      const bf16_t* b0p = &lds_b[cc * 1024];
      const bf16_t* b1p = &lds_b[(cc + 32) * 1024];
#pragma unroll 8
      for (int kc = 0; kc < 64; ++kc) {
        bf16x8 av = *(const bf16x8*)(ap + kc * 16);
        int kb = (kc * 2 + kh) ^ sw;
        bf16x8 b0 = *(const bf16x8*)(b0p + (kb << 3));
        bf16x8 b1 = *(const bf16x8*)(b1p + (kb << 3));
        if (kc & 1) {
          acB = __builtin_amdgcn_mfma_f32_32x32x16_bf16(av, b0, acB, 0, 0, 0);
          acD = __builtin_amdgcn_mfma_f32_32x32x16_bf16(av, b1, acD, 0, 0, 0);
        } else {
          acA = __builtin_amdgcn_mfma_f32_32x32x16_bf16(av, b0, acA, 0, 0, 0);
          acC = __builtin_amdgcn_mfma_f32_32x32x16_bf16(av, b1, acC, 0, 0, 0);
        }
      }
    }

    // gate exchange: lane pairs (cc, cc^16) hold complementary gate pairs
    float v0[16], v1[16], s0[16], s1[16];
#pragma unroll
    for (int r = 0; r < 16; ++r) {
      v0[r] = acA[r] + acB[r];
      v1[r] = acC[r] + acD[r];
      s0[r] = __shfl_xor(v0[r], 16);
      s1[r] = __shfl_xor(v1[r], 16);
    }

    const bf16_t* Gt = G + (LL)t * 512 * 4096;
    bf16_t* hw = hbuf[t & 1];
#pragma unroll
    for (int rr = 0; rr < 8; ++rr) {
      int reg = ga * 8 + rr;
      int row = (reg & 3) + 8 * (reg >> 2) + 4 * kh;
      LL m = m0 + w * 32 + row;
      float gi = ga ? s0[reg] : v0[reg];
      float gf = ga ? v0[reg] : s0[reg];
      float gg = ga ? s1[reg] : v1[reg];
      float go = ga ? v1[reg] : s1[reg];
      bf16x4 gq = *(const bf16x4*)(Gt + m * 4096 + 4 * unit);
      gi += (float)gq[0]; gf += (float)gq[1];
      gg += (float)gq[2]; go += (float)gq[3];
      float iv = sigm(gi), fv = sigm(gf), gv = tanh_s(gg), ov = sigm(go);
      float cn = fv * creg[rr] + iv * gv;
      creg[rr] = cn;
      float hn = ov * tanh_s(cn);
      hw[m * 1024 + unit] = (bf16_t)hn;
      hid[(m * 49 + t) * 1024 + unit] = hn;
    }

    if (t < 48) {
      __threadfence();       // release: h stores device-visible
      __syncthreads();
      if (tid == 0) {
        int* p = cnt + t * 4 + mt;
        __hip_atomic_fetch_add(p, 1, __ATOMIC_RELEASE, __HIP_MEMORY_SCOPE_AGENT);
        while (__hip_atomic_load(p, __ATOMIC_ACQUIRE,
                                 __HIP_MEMORY_SCOPE_AGENT) < 64) {}
      }
      __syncthreads();
      __threadfence();       // acquire: invalidate L1 before reading fresh h
    }
  }
}

// ==================== prep kernels ====================
__global__ __launch_bounds__(256)
void cvt_f2b(const float* __restrict__ src, bf16_t* __restrict__ dst, LL n4) {
  LL i = (LL)blockIdx.x * blockDim.x + threadIdx.x;
  LL stride = (LL)gridDim.x * blockDim.x;
  for (; i < n4; i += stride) {
    float4 v = *(const float4*)(src + i * 4);
    bf16x4 o;
    o[0] = (bf16_t)v.x; o[1] = (bf16_t)v.y; o[2] = (bf16_t)v.z; o[3] = (bf16_t)v.w;
    *(bf16x4*)(dst + i * 4) = o;
  }
}

// permuted row p = 4*j + g  maps from original row  g*1024 + j
__global__ __launch_bounds__(256)
void permute_w(const float* __restrict__ W, bf16_t* __restrict__ Wp) {
  int p = blockIdx.x;
  int r = (p & 3) * 1024 + (p >> 2);
  float4 v = *(const float4*)(W + (LL)r * 1024 + threadIdx.x * 4);
  bf16x4 o;
  o[0] = (bf16_t)v.x; o[1] = (bf16_t)v.y; o[2] = (bf16_t)v.z; o[3] = (bf16_t)v.w;
  *(bf16x4*)(Wp + (LL)p * 1024 + threadIdx.x * 4) = o;
}

__global__ __launch_bounds__(256)
void bias_comb(const float* __restrict__ bih, const float* __restrict__ bhh,
               float* __restrict__ bp) {
  int p = blockIdx.x * blockDim.x + threadIdx.x;
  int r = (p & 3) * 1024 + (p >> 2);
  bp[p] = bih[r] + bhh[r];
}

// Xb[slot][n][:] = bf16(emb[questions[n][tq]]) ; slot = tq + (fw?1:0)
__global__ __launch_bounds__(256)
void gather_emb(const int* __restrict__ q, const float* __restrict__ emb,
                bf16_t* __restrict__ Xb, const int* __restrict__ fw) {
  int b = blockIdx.x;
  int tq = b >> 9;
  int n = b & 511;
  int slot = fw[0] ? tq + 1 : tq;
  int row = q[n * 48 + tq];
  float4 v = *(const float4*)(emb + (LL)row * 1024 + threadIdx.x * 4);
  bf16x4 o;
  o[0] = (bf16_t)v.x; o[1] = (bf16_t)v.y; o[2] = (bf16_t)v.z; o[3] = (bf16_t)v.w;
  *(bf16x4*)(Xb + ((LL)slot * 512 + n) * 1024 + threadIdx.x * 4) = o;
}

// ==================== launch ====================
extern "C" void kernel_launch(void* const* d_in, const int* in_sizes, int n_in,
                              void* d_out, int out_size, void* d_ws,
                              size_t ws_size, hipStream_t stream) {
  const int*   questions = (const int*)  d_in[0];
  const float* img       = (const float*)d_in[1];
  const float* emb       = (const float*)d_in[2];
  const float* W_img     = (const float*)d_in[3];
  const float* b_img     = (const float*)d_in[4];
  const float* W_ih      = (const float*)d_in[5];
  const float* W_hh      = (const float*)d_in[6];
  const float* b_ih      = (const float*)d_in[7];
  const float* b_hh      = (const float*)d_in[8];
  const float* W_out     = (const float*)d_in[9];
  const float* b_out     = (const float*)d_in[10];
  const int*   fw        = (const int*)  d_in[11];

  char* ws = (char*)d_ws;
  size_t off = 0;
  auto alloc = [&](size_t bytes) {
    char* p = ws + off;
    off += (bytes + 255) & ~(size_t)255;
    return p;
  };
  bf16_t* Xb    = (bf16_t*)alloc((size_t)49 * 512 * 1024 * 2);   // 51.4 MB
  bf16_t* G     = (bf16_t*)alloc((size_t)49 * 512 * 4096 * 2);   // 205.5 MB
  bf16_t* Wp_ih = (bf16_t*)alloc((size_t)4096 * 1024 * 2);
  bf16_t* Whhb  = (bf16_t*)alloc((size_t)4096 * 1024 * 2);
  bf16_t* Woutb = (bf16_t*)alloc((size_t)32000 * 1024 * 2);      // 65.5 MB
  bf16_t* Wimgb = (bf16_t*)alloc((size_t)1024 * 4096 * 2);
  bf16_t* imgb  = (bf16_t*)alloc((size_t)512 * 4096 * 2);
  float*  biasp = (float*) alloc((size_t)4096 * 4);
  bf16_t* hb0   = (bf16_t*)alloc((size_t)512 * 1024 * 2);
  bf16_t* hb1   = (bf16_t*)alloc((size_t)512 * 1024 * 2);
  int*    cnt   = (int*)   alloc((size_t)49 * 4 * 4);

  float* out0 = (float*)d_out;
  float* hid  = out0 + (size_t)512 * 32000;

  hipMemsetAsync(cnt, 0, (size_t)49 * 4 * 4, stream);

  cvt_f2b<<<dim3(2048), dim3(256), 0, stream>>>(W_out, Woutb, (LL)32000 * 1024 / 4);
  cvt_f2b<<<dim3(1024), dim3(256), 0, stream>>>(W_img, Wimgb, (LL)1024 * 4096 / 4);
  cvt_f2b<<<dim3(512),  dim3(256), 0, stream>>>(img,   imgb,  (LL)512 * 4096 / 4);
  cvt_f2b<<<dim3(1024), dim3(256), 0, stream>>>(W_hh,  Whhb,  (LL)4096 * 1024 / 4);
  permute_w<<<dim3(4096), dim3(256), 0, stream>>>(W_ih, Wp_ih);
  bias_comb<<<dim3(16), dim3(256), 0, stream>>>(b_ih, b_hh, biasp);
  gather_emb<<<dim3(48 * 512), dim3(256), 0, stream>>>(questions, emb, Xb, fw);

  // emb_i = img @ W_img^T + b_img  -> Xb slot (fw ? 0 : 48), bf16
  gemm_bt<64, 1><<<dim3(8, 8), dim3(256), 0, stream>>>(
      imgb, Wimgb, b_img, Xb, nullptr, 1024, 4096, fw,
      (LL)48 * 512 * 1024, (LL)0);

  // G = Xb @ Wp_ih^T + (b_ih+b_hh)  (permuted cols), bf16  [25088 x 4096]
  gemm_bt<128, 1><<<dim3(196, 32), dim3(256), 0, stream>>>(
      Xb, Wp_ih, biasp, G, nullptr, 4096, 1024, fw, 0, 0);

  // all 49 recurrent steps in one persistent kernel
  lstm_persist<<<dim3(64, 4), dim3(256), 0, stream>>>(Whhb, G, hb0, hb1, hid, cnt);

  // output = h_48 @ W_out^T + b_out, fp32  [512 x 32000]
  gemm_bt<128, 0><<<dim3(4, 250), dim3(256), 0, stream>>>(
      hb0, Woutb, b_out, nullptr, out0, 32000, 1024, fw, 0, 0);
}